// Round 3
// baseline (7375.581 us; speedup 1.0000x reference)
//
#include <hip/hip_runtime.h>
#include <hip/hip_bf16.h>
#include <math.h>

#define HWD 262144   // 64*64*64

__device__ inline void store_bf16x16(__hip_bfloat16* p, const float* a) {
    unsigned short u[16];
#pragma unroll
    for (int i = 0; i < 16; ++i) {
        __hip_bfloat16 h = __float2bfloat16(a[i]);
        u[i] = *reinterpret_cast<unsigned short*>(&h);
    }
    uint4* q = reinterpret_cast<uint4*>(p);
    q[0] = *reinterpret_cast<const uint4*>(&u[0]);
    q[1] = *reinterpret_cast<const uint4*>(&u[8]);
}

// ---------------- prep: reorder w_c -> wc2[o][g][kd][tap], w_map -> wmT[k][c] ----------
__global__ void k_prep(const float* __restrict__ w_c, const float* __restrict__ w_map,
                       float* __restrict__ wc2, float* __restrict__ wmT) {
    int i = blockIdx.x * 256 + threadIdx.x;
    if (i < 147456) {
        // w_c flat: (((o*2+g)*3+dz)*3+dy)*64 + kd  = (og*9 + tap)*64 + kd
        int kd = i & 63;
        int r = i >> 6;
        int tap = r % 9;
        int og = r / 9;               // o*2+g
        wc2[og * 576 + kd * 9 + tap] = w_c[i];
    }
    if (i < 8192) {
        int k = i >> 6, c = i & 63;
        wmT[i] = w_map[c * 128 + k];  // wmT[k*64+c]
    }
}

// ---------------- transpose x (B,N,C) -> xg (B,C,N) ----------------
__global__ void k_transpose(const float* __restrict__ x, float* __restrict__ xg) {
    __shared__ float tile[64][65];
    int b = blockIdx.y;
    long n0 = (long)blockIdx.x * 64;
    int t = threadIdx.x;
    const float4* xp4 = (const float4*)(x + ((long)b * HWD + n0) * 64);
#pragma unroll
    for (int j = 0; j < 4; ++j) {
        int f4i = j * 256 + t;          // 0..1023
        float4 v = xp4[f4i];
        int row = f4i >> 4;             // n within tile
        int c4 = (f4i & 15) * 4;
        tile[c4 + 0][row] = v.x;
        tile[c4 + 1][row] = v.y;
        tile[c4 + 2][row] = v.z;
        tile[c4 + 3][row] = v.w;
    }
    __syncthreads();
    int c = t >> 2, sub = t & 3;
    float* xo = xg + (long)b * 64 * HWD + (long)c * HWD + n0 + sub * 16;
#pragma unroll
    for (int j2 = 0; j2 < 4; ++j2) {
        float4 v;
        v.x = tile[c][sub * 16 + j2 * 4 + 0];
        v.y = tile[c][sub * 16 + j2 * 4 + 1];
        v.z = tile[c][sub * 16 + j2 * 4 + 2];
        v.w = tile[c][sub * 16 + j2 * 4 + 3];
        ((float4*)xo)[j2] = v;
    }
}

// ---------------- transverse conv: T[b,c,w2,w,d] ----------------
// __launch_bounds__(256,3): VGPR cap 168 — acc[64]+tile operands ~100 VGPRs must NOT spill.
// Round-2 (256) defaulted to 48 VGPRs -> scratch spill -> 7x slowdown.
__global__ __launch_bounds__(256, 3) void k_conv_t(const float* __restrict__ xg,
        const float* __restrict__ w_t, const float* __restrict__ b_t,
        float* __restrict__ T) {
    int bid = blockIdx.x;
    int gidx = bid >> 5;            // 64 groups
    int strip = (bid >> 1) & 15;    // w strip of 4 rows
    int half = bid & 1;             // o half
    int b = gidx >> 5, ch = gidx & 31;
    int w0 = strip * 4;
    int oBase = half * 64;
    int t = threadIdx.x;
    int dw = t >> 6, d = t & 63;

    __shared__ float tile[2][6][66];

    float acc[64];
#pragma unroll
    for (int oo = 0; oo < 64; ++oo) acc[oo] = b_t[oBase + oo];

    const float* xbase = xg + ((long)(b * 64 + 2 * ch)) * HWD;

    int row0 = t / 66, col0 = t - row0 * 66;
    int wv0 = w0 - 1 + row0, dv0 = col0 - 1;
    bool ok0 = (wv0 >= 0) && (wv0 < 64) && (dv0 >= 0) && (dv0 < 64);
    int off0 = wv0 * 64 + dv0;
    int e1 = t + 256;
    int row1 = e1 / 66, col1 = e1 - row1 * 66;
    int wv1 = w0 - 1 + row1, dv1 = col1 - 1;
    bool has1 = t < 140;            // 396 elements total
    bool ok1 = has1 && (wv1 >= 0) && (wv1 < 64) && (dv1 >= 0) && (dv1 < 64);
    int off1 = wv1 * 64 + dv1;

    // stage m=0 (g=0, kh=0)
    tile[0][row0][col0] = ok0 ? xbase[off0] : 0.f;
    if (has1) tile[0][row1][col1] = ok1 ? xbase[off1] : 0.f;
    __syncthreads();

    for (int m = 0; m < 128; ++m) {
        int g = m >> 6, kh = m & 63;
        int buf = m & 1;
        float pv0 = 0.f, pv1 = 0.f;
        if (m < 127) {
            int m1 = m + 1;
            const float* plane = xbase + ((long)(m1 >> 6)) * HWD + (long)(m1 & 63) * 4096;
            if (ok0) pv0 = plane[off0];
            if (ok1) pv1 = plane[off1];
        }
        float x0 = tile[buf][dw][d],     x1 = tile[buf][dw][d + 1],     x2 = tile[buf][dw][d + 2];
        float x3 = tile[buf][dw + 1][d], x4 = tile[buf][dw + 1][d + 1], x5 = tile[buf][dw + 1][d + 2];
        float x6 = tile[buf][dw + 2][d], x7 = tile[buf][dw + 2][d + 1], x8 = tile[buf][dw + 2][d + 2];
        const float* wkb = w_t + (long)oBase * 1152 + g * 576 + kh * 9;
#pragma unroll
        for (int oo = 0; oo < 64; ++oo) {
            const float* wp = wkb + oo * 1152;   // uniform -> s_load
            float a = acc[oo];
            a = fmaf(wp[0], x0, a);
            a = fmaf(wp[1], x1, a);
            a = fmaf(wp[2], x2, a);
            a = fmaf(wp[3], x3, a);
            a = fmaf(wp[4], x4, a);
            a = fmaf(wp[5], x5, a);
            a = fmaf(wp[6], x6, a);
            a = fmaf(wp[7], x7, a);
            a = fmaf(wp[8], x8, a);
            acc[oo] = a;
        }
        if (m < 127) {
            int nb = buf ^ 1;
            tile[nb][row0][col0] = pv0;
            if (has1) tile[nb][row1][col1] = pv1;
        }
        __syncthreads();
    }

    int c = 2 * ch + half;
    float* outp = T + ((long)(b * 64 + c)) * HWD + (long)(w0 + dw) * 64 + d;
#pragma unroll
    for (int oo = 0; oo < 64; ++oo)
        outp[(long)oo * 4096] = acc[oo];        // w2 = oo
}

// ---------------- coronal conv: Cc[b,c,w2,h,w]  (written into d_out as scratch) ----------
__global__ __launch_bounds__(256, 3) void k_conv_c(const float* __restrict__ xg,
        const float* __restrict__ wc2, const float* __restrict__ b_c,
        float* __restrict__ Cc) {
    int bid = blockIdx.x;
    int gidx = bid >> 5;
    int strip = (bid >> 1) & 15;    // h strip of 4 rows
    int half = bid & 1;
    int b = gidx >> 5, ch = gidx & 31;
    int h0 = strip * 4;
    int oBase = half * 64;
    int t = threadIdx.x;
    int dh = t >> 6, w = t & 63;

    __shared__ float tile[6][16][66];   // [hrow][kd_sub][wcol]

    float acc[64];
#pragma unroll
    for (int oo = 0; oo < 64; ++oo) acc[oo] = b_c[oBase + oo];

    const float* xbase = xg + ((long)(b * 64 + 2 * ch)) * HWD;

    for (int cc = 0; cc < 8; ++cc) {
        int g = cc >> 2, kd0 = (cc & 3) * 16;
        __syncthreads();
        for (int e = t; e < 6336; e += 256) {
            int row = e / 1056;
            int rem = e - row * 1056;
            int wcol = rem >> 4, j = rem & 15;
            int hv = h0 - 1 + row, wv = wcol - 1;
            float v = 0.f;
            if (hv >= 0 && hv < 64 && wv >= 0 && wv < 64)
                v = xbase[(long)g * HWD + (long)hv * 4096 + wv * 64 + kd0 + j];
            tile[row][j][wcol] = v;
        }
        __syncthreads();
        for (int j = 0; j < 16; ++j) {
            float x0 = tile[dh][j][w],     x1 = tile[dh][j][w + 1],     x2 = tile[dh][j][w + 2];
            float x3 = tile[dh + 1][j][w], x4 = tile[dh + 1][j][w + 1], x5 = tile[dh + 1][j][w + 2];
            float x6 = tile[dh + 2][j][w], x7 = tile[dh + 2][j][w + 1], x8 = tile[dh + 2][j][w + 2];
            const float* wkb = wc2 + (long)oBase * 1152 + g * 576 + (kd0 + j) * 9;
#pragma unroll
            for (int oo = 0; oo < 64; ++oo) {
                const float* wp = wkb + oo * 1152;   // uniform -> s_load, 9 consecutive
                float a = acc[oo];
                a = fmaf(wp[0], x0, a);
                a = fmaf(wp[1], x1, a);
                a = fmaf(wp[2], x2, a);
                a = fmaf(wp[3], x3, a);
                a = fmaf(wp[4], x4, a);
                a = fmaf(wp[5], x5, a);
                a = fmaf(wp[6], x6, a);
                a = fmaf(wp[7], x7, a);
                a = fmaf(wp[8], x8, a);
                acc[oo] = a;
            }
        }
    }

    int c = 2 * ch + half;
    float* outp = Cc + ((long)(b * 64 + c)) * HWD + (long)(h0 + dh) * 64 + w;
#pragma unroll
    for (int oo = 0; oo < 64; ++oo)
        outp[(long)oo * 4096] = acc[oo];        // w2 = oo
}

// ---------------- attn: At[b,c,h,w2,d] = sum_w Cc[b,c,w2,h,w] * T[b,c,w2,w,d] (bf16 out) ----
__global__ void k_attn(const float* __restrict__ Cc, const float* __restrict__ T,
                       __hip_bfloat16* __restrict__ At) {
    __shared__ float As[64][65];
    __shared__ float Bs[64][64];
    int bc = blockIdx.x >> 6, w2 = blockIdx.x & 63;
    const float* Ap = Cc + ((long)bc * 64 + w2) * 4096;   // (h,w) plane, contiguous
    const float* Bp = T + ((long)bc * 64 + w2) * 4096;    // (w,d) plane, contiguous
    int t = threadIdx.x;
#pragma unroll
    for (int e0 = 0; e0 < 4096; e0 += 256) {
        int e = e0 + t;
        int r = e >> 6, q = e & 63;
        As[r][q] = Ap[e];
        Bs[r][q] = Bp[e];
    }
    __syncthreads();
    int h = t >> 2, dg = (t & 3) * 16;
    float acc[16];
#pragma unroll
    for (int i = 0; i < 16; ++i) acc[i] = 0.f;
    for (int k = 0; k < 64; ++k) {
        float a = As[h][k];
#pragma unroll
        for (int i = 0; i < 16; ++i)
            acc[i] = fmaf(a, Bs[k][dg + i], acc[i]);
    }
    __hip_bfloat16* Op = At + (long)bc * HWD + (long)h * 4096 + w2 * 64 + dg;
    store_bf16x16(Op, acc);
}

// ---------------- f: F[b,c,h,w,d] = sum_w2 Cc[b,c,w2,h,w] * T[b,c,w2,w,d] (bf16 out) ----
__global__ void k_f(const float* __restrict__ Cc, const float* __restrict__ T,
                    __hip_bfloat16* __restrict__ F) {
    __shared__ float As[64][65];   // As[h][w2]
    __shared__ float Bs[64][64];   // Bs[w2][d]
    int bc = blockIdx.x >> 6, w = blockIdx.x & 63;
    const float* Ab = Cc + (long)bc * HWD;
    const float* Bb = T + (long)bc * HWD + w * 64;
    int t = threadIdx.x;
#pragma unroll
    for (int e0 = 0; e0 < 4096; e0 += 256) {
        int e = e0 + t;
        int w2 = e >> 6, q = e & 63;
        As[q][w2] = Ab[(long)w2 * 4096 + q * 64 + w];   // scattered (L2-resident)
        Bs[w2][q] = Bb[(long)w2 * 4096 + q];
    }
    __syncthreads();
    int h = t >> 2, dg = (t & 3) * 16;
    float acc[16];
#pragma unroll
    for (int i = 0; i < 16; ++i) acc[i] = 0.f;
    for (int k = 0; k < 64; ++k) {
        float a = As[h][k];
#pragma unroll
        for (int i = 0; i < 16; ++i)
            acc[i] = fmaf(a, Bs[k][dg + i], acc[i]);
    }
    __hip_bfloat16* Op = F + (long)bc * HWD + (long)h * 4096 + w * 64 + dg;
    store_bf16x16(Op, acc);
}

// ---------------- map: out[b,n,c] = gelu( sum_k wm[c,k]*(x*F)[k] + wm[c,64+k]*At[k] + b_map[c] )
// shortcut read straight from x (B,N,C): thread n reads 64 contiguous floats.
__global__ __launch_bounds__(256, 4) void k_map(const float* __restrict__ x,
        const __hip_bfloat16* __restrict__ F, const __hip_bfloat16* __restrict__ At,
        const float* __restrict__ wmT, const float* __restrict__ b_map,
        float* __restrict__ out) {
    long n = (long)blockIdx.x * 256 + threadIdx.x;   // 0..B*HWD-1
    int b = (int)(n >> 18);
    long nn = n & (HWD - 1);
    const float* xp = x + n * 64;                    // contiguous per thread
    const __hip_bfloat16* fp = F + (long)b * 64 * HWD + nn;
    const __hip_bfloat16* ap = At + (long)b * 64 * HWD + nn;
    float acc[64];
#pragma unroll
    for (int c = 0; c < 64; ++c) acc[c] = b_map[c];
    for (int k = 0; k < 64; ++k) {
        float sf = xp[k] * __bfloat162float(fp[(long)k * HWD]);
        float av = __bfloat162float(ap[(long)k * HWD]);
        const float* w1 = wmT + k * 64;           // uniform rows -> s_load batches
        const float* w2 = wmT + (64 + k) * 64;
#pragma unroll
        for (int c = 0; c < 64; ++c)
            acc[c] = fmaf(w1[c], sf, fmaf(w2[c], av, acc[c]));
    }
#pragma unroll
    for (int c = 0; c < 64; ++c) {
        float v = acc[c];
        acc[c] = 0.5f * v * (1.f + erff(v * 0.70710678118654752440f));
    }
    float* op = out + n * 64;
#pragma unroll
    for (int q = 0; q < 16; ++q) {
        float4 v;
        v.x = acc[4 * q + 0];
        v.y = acc[4 * q + 1];
        v.z = acc[4 * q + 2];
        v.w = acc[4 * q + 3];
        ((float4*)op)[q] = v;
    }
}

extern "C" void kernel_launch(void* const* d_in, const int* in_sizes, int n_in,
                              void* d_out, int out_size, void* d_ws, size_t ws_size,
                              hipStream_t stream) {
    const float* x     = (const float*)d_in[0];
    const float* w_t   = (const float*)d_in[1];
    const float* b_t   = (const float*)d_in[2];
    const float* w_c   = (const float*)d_in[3];
    const float* b_c   = (const float*)d_in[4];
    const float* w_map = (const float*)d_in[5];
    const float* b_map = (const float*)d_in[6];
    float* out = (float*)d_out;
    float* ws = (float*)d_ws;

    // Workspace layout (269 MB total):
    //  R0 [0 .. 33.5M f)      : xg fp32; after convs dead -> reused for At/F bf16
    //  R1 [33.5M .. 67.1M f)  : T fp32
    //  weights at 67.1M f     : wc2 (147456) + wmT (8192)
    //  Cc fp32 lives in d_out (fully rewritten by k_map at the end)
    float* xg  = ws;
    float* T   = ws + 33554432L;
    float* Cc  = out;
    __hip_bfloat16* At_bf = (__hip_bfloat16*)ws;               // 67 MB (first half of R0)
    __hip_bfloat16* F_bf  = ((__hip_bfloat16*)ws) + 33554432L; // 67 MB (second half of R0)
    float* wc2 = ws + 67108864L;
    float* wmT = wc2 + 147456;

    hipLaunchKernelGGL(k_prep, dim3(576), dim3(256), 0, stream, w_c, w_map, wc2, wmT);
    hipLaunchKernelGGL(k_transpose, dim3(4096, 2), dim3(256), 0, stream, x, xg);
    hipLaunchKernelGGL(k_conv_t, dim3(2048), dim3(256), 0, stream, xg, w_t, b_t, T);
    hipLaunchKernelGGL(k_conv_c, dim3(2048), dim3(256), 0, stream, xg, wc2, b_c, Cc);
    hipLaunchKernelGGL(k_attn, dim3(8192), dim3(256), 0, stream, Cc, T, At_bf);
    hipLaunchKernelGGL(k_f, dim3(8192), dim3(256), 0, stream, Cc, T, F_bf);
    hipLaunchKernelGGL(k_map, dim3(2048), dim3(256), 0, stream, x, F_bf, At_bf, wmT, b_map, out);
}

// Round 4
// 1224.521 us; speedup vs baseline: 6.0232x; 6.0232x over previous
//
#include <hip/hip_runtime.h>
#include <hip/hip_bf16.h>
#include <math.h>

#define HWD 262144   // 64*64*64

typedef __attribute__((ext_vector_type(8))) short bf16x8;   // 8 bf16 (4 VGPRs)
typedef __attribute__((ext_vector_type(16))) float f32x16;  // MFMA 32x32 accumulator

// ---------------- prep: weights -> bf16 GEMM layout A[ks 72][oc 128][kk 16]; w_map -> wmT ----
// K order: k = ((g*3+r)*3+s)*64 + z,  ks=k>>4, kk=k&15.
__global__ void k_prep(const float* __restrict__ w_t, const float* __restrict__ w_c,
                       const float* __restrict__ w_map,
                       __hip_bfloat16* __restrict__ A_t, __hip_bfloat16* __restrict__ A_c,
                       float* __restrict__ wmT) {
    int i = blockIdx.x * 256 + threadIdx.x;
    if (i < 147456) {
        int kk = i & 15, oc = (i >> 4) & 127, ks = i >> 11;
        int z4 = ks & 3, kq = ks >> 2;          // kq = (g*3+r)*3+s in [0,18)
        int g = kq / 9, tap = kq - 9 * g;       // tap = r*3+s
        int z = z4 * 16 + kk;
        // w_t (128,2,64,3,3): ((o*2+g)*64+kh)*9 + tap,  z=kh
        A_t[i] = __float2bfloat16(w_t[((oc * 2 + g) * 64 + z) * 9 + tap]);
        // w_c (128,2,3,3,64): ((o*2+g)*9+tap)*64 + kd,  z=kd
        A_c[i] = __float2bfloat16(w_c[((oc * 2 + g) * 9 + tap) * 64 + z]);
    }
    if (i < 8192) {
        wmT[i] = w_map[(i & 63) * 128 + (i >> 6)];   // wmT[k][c]
    }
}

__device__ inline void pack_row_bf16(__hip_bfloat16* dst, const float* src) {
    unsigned short u[16];
#pragma unroll
    for (int j = 0; j < 16; ++j) {
        __hip_bfloat16 h = __float2bfloat16(src[j]);
        u[j] = *reinterpret_cast<unsigned short*>(&h);
    }
    uint4* q = reinterpret_cast<uint4*>(dst);
    q[0] = *reinterpret_cast<const uint4*>(&u[0]);
    q[1] = *reinterpret_cast<const uint4*>(&u[8]);
}

// ---------------- transpose x (B,N,C) -> Xc bf16 [cg][h][w][d] ----------------
__global__ void k_trans_c(const float* __restrict__ x, __hip_bfloat16* __restrict__ Xc) {
    __shared__ float tile[64][65];
    int b = blockIdx.y;
    long n0 = (long)blockIdx.x * 64;
    int t = threadIdx.x;
    const float4* xp4 = (const float4*)(x + ((long)b * HWD + n0) * 64);
#pragma unroll
    for (int j = 0; j < 4; ++j) {
        int f4i = j * 256 + t;
        float4 v = xp4[f4i];
        int row = f4i >> 4;
        int c4 = (f4i & 15) * 4;
        tile[c4 + 0][row] = v.x;
        tile[c4 + 1][row] = v.y;
        tile[c4 + 2][row] = v.z;
        tile[c4 + 3][row] = v.w;
    }
    __syncthreads();
    int c = t >> 2, sub = t & 3;
    pack_row_bf16(Xc + (long)(b * 64 + c) * HWD + n0 + sub * 16, &tile[c][sub * 16]);
}

// ---------------- transpose x -> Xt bf16 [cg][w][d][h] ----------------
__global__ void k_trans_t(const float* __restrict__ x, __hip_bfloat16* __restrict__ Xt) {
    __shared__ float tile[64][65];   // [c][h]
    int b = blockIdx.y;
    int wd = blockIdx.x;             // w*64+d
    int t = threadIdx.x;
#pragma unroll
    for (int j = 0; j < 4; ++j) {
        int f4i = j * 256 + t;       // 64 h x 16 c-quads
        int h = f4i >> 4;
        int c4 = (f4i & 15) * 4;
        float4 v = *(const float4*)(x + ((long)b * HWD + (long)h * 4096 + wd) * 64 + c4);
        tile[c4 + 0][h] = v.x;
        tile[c4 + 1][h] = v.y;
        tile[c4 + 2][h] = v.z;
        tile[c4 + 3][h] = v.w;
    }
    __syncthreads();
    int c = t >> 2, sub = t & 3;
    pack_row_bf16(Xt + (long)(b * 64 + c) * HWD + (long)wd * 64 + sub * 16, &tile[c][sub * 16]);
}

// ---------------- unified MFMA conv: per (b,ch) GEMM C[128][4096] = A[128][1152] * B ----------
// B[k=(g,r,s,z)][n=(p,q)] = X[2ch+g][p+r-1][q+s-1][z]  (implicit im2col via address shifts)
// conv_t: X=Xt (p=w,q=d,z=kh) -> T[b][c][w2][w][d];  conv_c: X=Xc (p=h,q=w,z=kd) -> Cc[b][c][w2][h][w]
__global__ __launch_bounds__(256, 4) void k_conv_mfma(
        const __hip_bfloat16* __restrict__ X, const __hip_bfloat16* __restrict__ Aglob,
        const float* __restrict__ bias, float* __restrict__ Out) {
    int blk = blockIdx.x;
    int grp = blk >> 5;             // b*32+ch
    int pt = blk & 31;              // p-tile: 2 p-rows
    int b = grp >> 5, ch = grp & 31;
    int p0 = pt * 2;
    const __hip_bfloat16* Xg = X + ((long)(b * 64 + 2 * ch)) * HWD;
    int t = threadIdx.x;
    int lane = t & 63, wv = t >> 6;

    __shared__ short Asm[128 * 24];   // rows: 16 data bf16 + 8 pad = 48B
    __shared__ short Bsm[128 * 24];

    f32x16 acc00 = {0}, acc01 = {0}, acc10 = {0}, acc11 = {0};

    int srow = t >> 1, shalf = t & 1;     // staging: row 0..127, 16B half
    int pr = srow >> 6, q = srow & 63;    // B-row -> (p-row, q)
    int O0 = (wv >> 1) * 64;              // wave oc base
    int N0 = (wv & 1) * 64;               // wave n base
    int lrow = lane & 31, lq = lane >> 5;

    for (int ks = 0; ks < 72; ++ks) {
        int z4 = ks & 3, kq = ks >> 2;
        int g = kq / 9, tap = kq - 9 * g;
        int r = tap / 3, s = tap - 3 * r;
        // A stage: contiguous 4KB
        uint4 av = *(const uint4*)(Aglob + ks * 2048 + t * 8);
        // B stage: predicated 16B from X
        int pp = p0 + pr + r - 1, qq = q + s - 1;
        uint4 bv = {0u, 0u, 0u, 0u};
        if (pp >= 0 && pp < 64 && qq >= 0 && qq < 64)
            bv = *(const uint4*)(Xg + (long)g * HWD + ((pp << 6) + qq) * 64 + z4 * 16 + shalf * 8);
        __syncthreads();
        *(uint4*)(Asm + srow * 24 + shalf * 8) = av;
        *(uint4*)(Bsm + srow * 24 + shalf * 8) = bv;
        __syncthreads();
        bf16x8 a0 = *(const bf16x8*)(Asm + (O0 + lrow) * 24 + lq * 8);
        bf16x8 a1 = *(const bf16x8*)(Asm + (O0 + 32 + lrow) * 24 + lq * 8);
        bf16x8 b0 = *(const bf16x8*)(Bsm + (N0 + lrow) * 24 + lq * 8);
        bf16x8 b1 = *(const bf16x8*)(Bsm + (N0 + 32 + lrow) * 24 + lq * 8);
        acc00 = __builtin_amdgcn_mfma_f32_32x32x16_bf16(a0, b0, acc00, 0, 0, 0);
        acc01 = __builtin_amdgcn_mfma_f32_32x32x16_bf16(a0, b1, acc01, 0, 0, 0);
        acc10 = __builtin_amdgcn_mfma_f32_32x32x16_bf16(a1, b0, acc10, 0, 0, 0);
        acc11 = __builtin_amdgcn_mfma_f32_32x32x16_bf16(a1, b1, acc11, 0, 0, 0);
    }

    // store: C/D layout col=lane&31, row=(reg&3)+8*(reg>>2)+4*(lane>>5)
    long base0 = ((long)(b * 64 + 2 * ch)) * HWD + (long)p0 * 64;
    int n0l = N0 + lrow, n1l = N0 + 32 + lrow;
    long noff0 = (long)(n0l >> 6) * 64 + (n0l & 63);
    long noff1 = (long)(n1l >> 6) * 64 + (n1l & 63);
#pragma unroll
    for (int reg = 0; reg < 16; ++reg) {
        int row = (reg & 3) + 8 * (reg >> 2) + 4 * lq;
        int oc0 = O0 + row, oc1 = O0 + 32 + row;
        long cb0 = base0 + (long)(oc0 >> 6) * HWD + (long)(oc0 & 63) * 4096;
        long cb1 = base0 + (long)(oc1 >> 6) * HWD + (long)(oc1 & 63) * 4096;
        float bs0 = bias[oc0], bs1 = bias[oc1];
        Out[cb0 + noff0] = acc00[reg] + bs0;
        Out[cb0 + noff1] = acc01[reg] + bs0;
        Out[cb1 + noff0] = acc10[reg] + bs1;
        Out[cb1 + noff1] = acc11[reg] + bs1;
    }
}

// ---------------- attn: At[b,c,h,w2,d] = sum_w Cc[b,c,w2,h,w] * T[b,c,w2,w,d] (bf16 out) ----
__global__ void k_attn(const float* __restrict__ Cc, const float* __restrict__ T,
                       __hip_bfloat16* __restrict__ At) {
    __shared__ float As[64][65];
    __shared__ float Bs[64][64];
    int bc = blockIdx.x >> 6, w2 = blockIdx.x & 63;
    const float* Ap = Cc + ((long)bc * 64 + w2) * 4096;
    const float* Bp = T + ((long)bc * 64 + w2) * 4096;
    int t = threadIdx.x;
#pragma unroll
    for (int e0 = 0; e0 < 4096; e0 += 256) {
        int e = e0 + t;
        int r = e >> 6, q = e & 63;
        As[r][q] = Ap[e];
        Bs[r][q] = Bp[e];
    }
    __syncthreads();
    int h = t >> 2, dg = (t & 3) * 16;
    f32x16 acc = {0};
    for (int k = 0; k < 64; ++k) {
        float a = As[h][k];
#pragma unroll
        for (int i = 0; i < 16; ++i)
            acc[i] = fmaf(a, Bs[k][dg + i], acc[i]);
    }
    float tmp[16];
#pragma unroll
    for (int i = 0; i < 16; ++i) tmp[i] = acc[i];
    pack_row_bf16(At + (long)bc * HWD + (long)h * 4096 + w2 * 64 + dg, tmp);
}

// ---------------- f: F[b,c,h,w,d] = sum_w2 Cc[b,c,w2,h,w] * T[b,c,w2,w,d] (bf16 out) ----
__global__ void k_f(const float* __restrict__ Cc, const float* __restrict__ T,
                    __hip_bfloat16* __restrict__ F) {
    __shared__ float As[64][65];   // [h][w2]
    __shared__ float Bs[64][64];   // [w2][d]
    int bc = blockIdx.x >> 6, w = blockIdx.x & 63;
    const float* Ab = Cc + (long)bc * HWD;
    const float* Bb = T + (long)bc * HWD + w * 64;
    int t = threadIdx.x;
#pragma unroll
    for (int e0 = 0; e0 < 4096; e0 += 256) {
        int e = e0 + t;
        int w2 = e >> 6, q = e & 63;
        As[q][w2] = Ab[(long)w2 * 4096 + q * 64 + w];
        Bs[w2][q] = Bb[(long)w2 * 4096 + q];
    }
    __syncthreads();
    int h = t >> 2, dg = (t & 3) * 16;
    f32x16 acc = {0};
    for (int k = 0; k < 64; ++k) {
        float a = As[h][k];
#pragma unroll
        for (int i = 0; i < 16; ++i)
            acc[i] = fmaf(a, Bs[k][dg + i], acc[i]);
    }
    float tmp[16];
#pragma unroll
    for (int i = 0; i < 16; ++i) tmp[i] = acc[i];
    pack_row_bf16(F + (long)bc * HWD + (long)h * 4096 + w * 64 + dg, tmp);
}

// ---------------- map: out[b,n,c] = gelu( wm[c,:64].(x*F) + wm[c,64:].At + b_map[c] ) ------
// accumulators as 4 named f32x16 vectors (NO arrays -> no scratch spill).
__global__ __launch_bounds__(256, 4) void k_map(const float* __restrict__ x,
        const __hip_bfloat16* __restrict__ F, const __hip_bfloat16* __restrict__ At,
        const float* __restrict__ wmT, const float* __restrict__ b_map,
        float* __restrict__ out) {
    long n = (long)blockIdx.x * 256 + threadIdx.x;
    int b = (int)(n >> 18);
    long nn = n & (HWD - 1);
    const float* xp = x + n * 64;
    const __hip_bfloat16* fp = F + (long)b * 64 * HWD + nn;
    const __hip_bfloat16* ap = At + (long)b * 64 * HWD + nn;
    f32x16 A0, A1, A2, A3;
#pragma unroll
    for (int i = 0; i < 16; ++i) {
        A0[i] = b_map[i];
        A1[i] = b_map[16 + i];
        A2[i] = b_map[32 + i];
        A3[i] = b_map[48 + i];
    }
    for (int k = 0; k < 64; ++k) {
        float sf = xp[k] * __bfloat162float(fp[(long)k * HWD]);
        float av = __bfloat162float(ap[(long)k * HWD]);
        const float* w1 = wmT + k * 64;
        const float* w2 = wmT + 4096 + k * 64;
#pragma unroll
        for (int i = 0; i < 16; ++i) {
            A0[i] = fmaf(w1[i], sf, fmaf(w2[i], av, A0[i]));
            A1[i] = fmaf(w1[16 + i], sf, fmaf(w2[16 + i], av, A1[i]));
            A2[i] = fmaf(w1[32 + i], sf, fmaf(w2[32 + i], av, A2[i]));
            A3[i] = fmaf(w1[48 + i], sf, fmaf(w2[48 + i], av, A3[i]));
        }
    }
    const float inv_sqrt2 = 0.70710678118654752440f;
#pragma unroll
    for (int i = 0; i < 16; ++i) {
        A0[i] = 0.5f * A0[i] * (1.f + erff(A0[i] * inv_sqrt2));
        A1[i] = 0.5f * A1[i] * (1.f + erff(A1[i] * inv_sqrt2));
        A2[i] = 0.5f * A2[i] * (1.f + erff(A2[i] * inv_sqrt2));
        A3[i] = 0.5f * A3[i] * (1.f + erff(A3[i] * inv_sqrt2));
    }
    float* op = out + n * 64;
#pragma unroll
    for (int qd = 0; qd < 4; ++qd) {
        float4 v0, v1, v2, v3;
        v0.x = A0[4 * qd]; v0.y = A0[4 * qd + 1]; v0.z = A0[4 * qd + 2]; v0.w = A0[4 * qd + 3];
        v1.x = A1[4 * qd]; v1.y = A1[4 * qd + 1]; v1.z = A1[4 * qd + 2]; v1.w = A1[4 * qd + 3];
        v2.x = A2[4 * qd]; v2.y = A2[4 * qd + 1]; v2.z = A2[4 * qd + 2]; v2.w = A2[4 * qd + 3];
        v3.x = A3[4 * qd]; v3.y = A3[4 * qd + 1]; v3.z = A3[4 * qd + 2]; v3.w = A3[4 * qd + 3];
        ((float4*)op)[qd] = v0;
        ((float4*)op)[4 + qd] = v1;
        ((float4*)op)[8 + qd] = v2;
        ((float4*)op)[12 + qd] = v3;
    }
}

extern "C" void kernel_launch(void* const* d_in, const int* in_sizes, int n_in,
                              void* d_out, int out_size, void* d_ws, size_t ws_size,
                              hipStream_t stream) {
    const float* x     = (const float*)d_in[0];
    const float* w_t   = (const float*)d_in[1];
    const float* b_t   = (const float*)d_in[2];
    const float* w_c   = (const float*)d_in[3];
    const float* b_c   = (const float*)d_in[4];
    const float* w_map = (const float*)d_in[5];
    const float* b_map = (const float*)d_in[6];
    float* out = (float*)d_out;
    float* ws = (float*)d_ws;

    // ws layout (float offsets), ~269 MB total:
    //  [0,        16777216)  Xc bf16  (33.5M elem)  -> reused as At bf16 after conv_c
    //  [16777216, 33554432)  Xt bf16                -> reused as F bf16 after conv_t
    //  [33554432, 67108864)  T fp32
    //  [67108864, ...)       A_t bf16 (147456) | A_c bf16 (147456) | wmT f32 (8192)
    __hip_bfloat16* Xc = (__hip_bfloat16*)ws;
    __hip_bfloat16* Xt = (__hip_bfloat16*)(ws + 16777216L);
    float* T = ws + 33554432L;
    float* Cc = out;                                     // d_out as scratch
    __hip_bfloat16* A_t = (__hip_bfloat16*)(ws + 67108864L);
    __hip_bfloat16* A_c = (__hip_bfloat16*)(ws + 67182592L);
    float* wmT = ws + 67256320L;
    __hip_bfloat16* At_bf = Xc;                          // 67 MB, Xc dead after convs
    __hip_bfloat16* F_bf = Xt;                           // 67 MB, Xt dead after convs

    hipLaunchKernelGGL(k_prep, dim3(576), dim3(256), 0, stream, w_t, w_c, w_map, A_t, A_c, wmT);
    hipLaunchKernelGGL(k_trans_c, dim3(4096, 2), dim3(256), 0, stream, x, Xc);
    hipLaunchKernelGGL(k_trans_t, dim3(4096, 2), dim3(256), 0, stream, x, Xt);
    hipLaunchKernelGGL(k_conv_mfma, dim3(2048), dim3(256), 0, stream, Xt, A_t, b_t, T);
    hipLaunchKernelGGL(k_conv_mfma, dim3(2048), dim3(256), 0, stream, Xc, A_c, b_c, Cc);
    hipLaunchKernelGGL(k_attn, dim3(8192), dim3(256), 0, stream, Cc, T, At_bf);
    hipLaunchKernelGGL(k_f, dim3(8192), dim3(256), 0, stream, Cc, T, F_bf);
    hipLaunchKernelGGL(k_map, dim3(2048), dim3(256), 0, stream, x, F_bf, At_bf, wmT, b_map, out);
}